// Round 1
// baseline (759.159 us; speedup 1.0000x reference)
//
#include <hip/hip_runtime.h>
#include <cstdint>

// GAT layer, fused single kernel, fp32 VALU.
// Layout: block = 256 threads = 4 waves; wave h owns head h; lane = local agent.
// TILE = 64 agents/block; N = 200000 = 3125 * 64 exactly (no tail).
#define TILE 64
#define XSTRIDE 68    // 64-float row padded to 68 (16B aligned, conflict-free b128)
#define OSTRIDE 132   // 128-float row padded to 132

__global__ __launch_bounds__(256, 4)
void gat_fused(const float* __restrict__ agent,
               const float* __restrict__ neighbor,
               const int*   __restrict__ nmask,
               const float* __restrict__ Wa, const float* __restrict__ ba,
               const float* __restrict__ Wn, const float* __restrict__ bn,
               const float* __restrict__ Wh, const float* __restrict__ bh,
               const float* __restrict__ Wo, const float* __restrict__ bo,
               float* __restrict__ out)
{
    __shared__ float smem[TILE * OSTRIDE];   // 33792 B; xbuf (A-D) then obuf (E)
    float* xbuf = smem;

    const int tid  = threadIdx.x;
    const int lane = tid & 63;                                   // local agent
    const int h    = __builtin_amdgcn_readfirstlane(tid >> 6);   // wave id = head (uniform!)
    const int h32  = h * 32;
    const long base = (long)blockIdx.x * TILE;

    // ---------------- stage agent tile (coalesced float4) ----------------
    {
        const float* src = agent + base * 64;
        #pragma unroll
        for (int it = 0; it < 4; ++it) {
            int f = tid + it * 256;           // float4 index in [0, TILE*16)
            int r = f >> 4, c = (f & 15) << 2;
            float4 v = *(const float4*)(src + (long)f * 4);
            *(float4*)(xbuf + r * XSTRIDE + c) = v;
        }
    }
    __syncthreads();

    // ---------------- phase A: a_h[32] = relu(x_a @ Wa + ba) -------------
    float a_acc[32];
    #pragma unroll
    for (int m = 0; m < 32; ++m) a_acc[m] = ba[h32 + m];
    {
        const float4* xr = (const float4*)(xbuf + lane * XSTRIDE);
        #pragma unroll 4
        for (int kc = 0; kc < 16; ++kc) {
            float4 x = xr[kc];
            const float* w0 = Wa + (kc * 4) * 128 + h32;   // uniform -> s_load
            const float* w1 = w0 + 128;
            const float* w2 = w0 + 256;
            const float* w3 = w0 + 384;
            #pragma unroll
            for (int m = 0; m < 32; ++m)
                a_acc[m] += x.x * w0[m] + x.y * w1[m] + x.z * w2[m] + x.w * w3[m];
        }
    }
    #pragma unroll
    for (int m = 0; m < 32; ++m) a_acc[m] = fmaxf(a_acc[m], 0.0f);

    // ---------------- phase B: attention logits (fused W_neigh proj) -----
    float logit[4];
    #pragma unroll 1
    for (int k = 0; k < 4; ++k) {
        __syncthreads();
        #pragma unroll
        for (int it = 0; it < 4; ++it) {
            int f = tid + it * 256;
            int r = f >> 4, c = (f & 15) << 2;
            float4 v = *(const float4*)(neighbor + ((base + r) * 4 + k) * 64 + c);
            *(float4*)(xbuf + r * XSTRIDE + c) = v;
        }
        __syncthreads();
        float acc[32];
        #pragma unroll
        for (int m = 0; m < 32; ++m) acc[m] = bn[h32 + m];
        const float4* xr = (const float4*)(xbuf + lane * XSTRIDE);
        #pragma unroll 4
        for (int kc = 0; kc < 16; ++kc) {
            float4 x = xr[kc];
            const float* w0 = Wn + (kc * 4) * 128 + h32;
            const float* w1 = w0 + 128;
            const float* w2 = w0 + 256;
            const float* w3 = w0 + 384;
            #pragma unroll
            for (int m = 0; m < 32; ++m)
                acc[m] += x.x * w0[m] + x.y * w1[m] + x.z * w2[m] + x.w * w3[m];
        }
        float lg = 0.0f;
        #pragma unroll
        for (int m = 0; m < 32; ++m) lg += a_acc[m] * fmaxf(acc[m], 0.0f);
        logit[k] = lg;
    }

    // ---------------- phase C: masked softmax over k (per lane) ----------
    float score[4];
    {
        const int4 mi = *(const int4*)(nmask + (base + lane) * 4);
        float mk[4] = { (float)mi.x, (float)mi.y, (float)mi.z, (float)mi.w };
        float s[4];
        float mx = -1e30f;
        #pragma unroll
        for (int k = 0; k < 4; ++k) {
            s[k] = mk[k] * -1e8f + logit[k];
            mx = fmaxf(mx, s[k]);
        }
        float e[4], sum = 0.0f;
        #pragma unroll
        for (int k = 0; k < 4; ++k) { e[k] = __expf(s[k] - mx); sum += e[k]; }
        float inv = 0.25f / sum;   // fold the /4 mean here
        #pragma unroll
        for (int k = 0; k < 4; ++k) score[k] = (1.0f - mk[k]) * e[k] * inv;
    }

    // ---------------- phase D: out_h[32] = sum_k score_k * relu(x_nk@Wh+bh)
    float oacc[32];
    #pragma unroll
    for (int m = 0; m < 32; ++m) oacc[m] = 0.0f;
    #pragma unroll 1
    for (int k = 0; k < 4; ++k) {
        __syncthreads();
        #pragma unroll
        for (int it = 0; it < 4; ++it) {
            int f = tid + it * 256;
            int r = f >> 4, c = (f & 15) << 2;
            float4 v = *(const float4*)(neighbor + ((base + r) * 4 + k) * 64 + c);
            *(float4*)(xbuf + r * XSTRIDE + c) = v;
        }
        __syncthreads();
        float acc[32];
        #pragma unroll
        for (int m = 0; m < 32; ++m) acc[m] = bh[h32 + m];
        const float4* xr = (const float4*)(xbuf + lane * XSTRIDE);
        #pragma unroll 4
        for (int kc = 0; kc < 16; ++kc) {
            float4 x = xr[kc];
            const float* w0 = Wh + (kc * 4) * 128 + h32;
            const float* w1 = w0 + 128;
            const float* w2 = w0 + 256;
            const float* w3 = w0 + 384;
            #pragma unroll
            for (int m = 0; m < 32; ++m)
                acc[m] += x.x * w0[m] + x.y * w1[m] + x.z * w2[m] + x.w * w3[m];
        }
        float sk = score[k];
        #pragma unroll
        for (int m = 0; m < 32; ++m) oacc[m] += sk * fmaxf(acc[m], 0.0f);
    }

    // ---------------- phase E: y = relu(out @ Wo + bo), cross-head --------
    __syncthreads();                      // xbuf dead; reuse smem as obuf
    float* obuf = smem;
    #pragma unroll
    for (int mc = 0; mc < 8; ++mc) {
        float4 v = make_float4(oacc[mc * 4], oacc[mc * 4 + 1],
                               oacc[mc * 4 + 2], oacc[mc * 4 + 3]);
        *(float4*)(obuf + lane * OSTRIDE + h32 + mc * 4) = v;
    }
    __syncthreads();

    const int j0 = h * 16;                // wave h owns output cols [j0, j0+16)
    float yacc[16];
    #pragma unroll
    for (int jj = 0; jj < 16; ++jj) yacc[jj] = bo[j0 + jj];
    {
        const float4* orow = (const float4*)(obuf + lane * OSTRIDE);
        #pragma unroll 4
        for (int tc = 0; tc < 32; ++tc) {
            float4 x = orow[tc];
            const float* w0 = Wo + (tc * 4) * 64 + j0;   // uniform -> s_load
            const float* w1 = w0 + 64;
            const float* w2 = w0 + 128;
            const float* w3 = w0 + 192;
            #pragma unroll
            for (int jj = 0; jj < 16; ++jj)
                yacc[jj] += x.x * w0[jj] + x.y * w1[jj] + x.z * w2[jj] + x.w * w3[jj];
        }
    }
    float* dst = out + (base + lane) * 64 + j0;
    #pragma unroll
    for (int jc = 0; jc < 4; ++jc) {
        float4 v = make_float4(fmaxf(yacc[jc * 4], 0.0f),
                               fmaxf(yacc[jc * 4 + 1], 0.0f),
                               fmaxf(yacc[jc * 4 + 2], 0.0f),
                               fmaxf(yacc[jc * 4 + 3], 0.0f));
        *(float4*)(dst + jc * 4) = v;
    }
}

extern "C" void kernel_launch(void* const* d_in, const int* in_sizes, int n_in,
                              void* d_out, int out_size, void* d_ws, size_t ws_size,
                              hipStream_t stream) {
    const float* agent    = (const float*)d_in[0];
    const float* neighbor = (const float*)d_in[1];
    const int*   nmask    = (const int*)d_in[2];
    const float* Wa = (const float*)d_in[3];
    const float* ba = (const float*)d_in[4];
    const float* Wn = (const float*)d_in[5];
    const float* bn = (const float*)d_in[6];
    const float* Wh = (const float*)d_in[7];
    const float* bh = (const float*)d_in[8];
    const float* Wo = (const float*)d_in[9];
    const float* bo = (const float*)d_in[10];
    float* out = (float*)d_out;

    const int n = in_sizes[0] / 64;       // 200000
    const int blocks = n / TILE;          // 3125 (exact)
    gat_fused<<<blocks, 256, 0, stream>>>(agent, neighbor, nmask,
                                          Wa, ba, Wn, bn, Wh, bh, Wo, bo, out);
}

// Round 4
// 415.615 us; speedup vs baseline: 1.8266x; 1.8266x over previous
//
#include <hip/hip_runtime.h>
#include <cstdint>

// GAT layer via f16 MFMA. Block = 256 thr = 4 waves; wave h = head h.
// TILE = 64 agents/block, N = 200000 = 3125 * 64 exactly.
// C-layout (16x16 MFMA): col = lane&15, row = (lane>>4)*4 + reg.
// A-frag: row m = lane&15, k = (lane>>4)*8 + j  -> lane must load its q*8 k-slice!
// B-frag: col n = lane&15, k = (lane>>4)*8 + j  (weights pre-transposed [n][k] f16 in ws).

typedef _Float16 f16;
typedef f16 f16x8 __attribute__((ext_vector_type(8)));
typedef float f32x4 __attribute__((ext_vector_type(4)));

#define MFMA(a, b, c) __builtin_amdgcn_mfma_f32_16x16x32_f16(a, b, c, 0, 0, 0)

// 8 floats -> 8 f16, RNE (v_cvt_f16_f32), from 2 float4 loads
__device__ __forceinline__ f16x8 ld_cvt8(const float* __restrict__ p) {
    float4 a = *(const float4*)p;
    float4 b = *(const float4*)(p + 4);
    f16x8 r;
    r[0] = (f16)a.x; r[1] = (f16)a.y; r[2] = (f16)a.z; r[3] = (f16)a.w;
    r[4] = (f16)b.x; r[5] = (f16)b.y; r[6] = (f16)b.z; r[7] = (f16)b.w;
    return r;
}

// Sum across the 16 lanes of a DPP row (all lanes get the total). VALU pipe.
__device__ __forceinline__ float rowsum16(float x) {
    x += __int_as_float(__builtin_amdgcn_update_dpp(0, __float_as_int(x), 0x128, 0xf, 0xf, true)); // row_ror:8
    x += __int_as_float(__builtin_amdgcn_update_dpp(0, __float_as_int(x), 0x124, 0xf, 0xf, true)); // row_ror:4
    x += __int_as_float(__builtin_amdgcn_update_dpp(0, __float_as_int(x), 0x122, 0xf, 0xf, true)); // row_ror:2
    x += __int_as_float(__builtin_amdgcn_update_dpp(0, __float_as_int(x), 0x121, 0xf, 0xf, true)); // row_ror:1
    return x;
}

// ---- prep: transpose+convert weights to f16 [n][k] in ws ----
// ws layout (f16): Wt_a [128][64] @0, Wt_n @8192, Wt_h @16384, Wt_o [64][128] @24576
__global__ void prep_w(const float* __restrict__ Wa, const float* __restrict__ Wn,
                       const float* __restrict__ Wh, const float* __restrict__ Wo,
                       f16* __restrict__ ws) {
    int i = blockIdx.x * 256 + threadIdx.x;   // 0..32767
    int m = i >> 13;                          // matrix id 0..3
    int j = i & 8191;
    if (m < 3) {
        const float* W = (m == 0) ? Wa : ((m == 1) ? Wn : Wh);
        int n = j >> 6, k = j & 63;           // Wt[n][k] = W[k][n], W is [64][128]
        ws[m * 8192 + j] = (f16)W[k * 128 + n];
    } else {
        int n = j >> 7, k = j & 127;          // Wt_o[n][k] = Wo[k][n], Wo is [128][64]
        ws[24576 + j] = (f16)Wo[k * 64 + n];
    }
}

__global__ __launch_bounds__(256, 2)
void gat_mfma(const float* __restrict__ agent,
              const float* __restrict__ neighbor,
              const int*   __restrict__ nmask,
              const f16*   __restrict__ ws,
              const float* __restrict__ ba, const float* __restrict__ bn,
              const float* __restrict__ bh, const float* __restrict__ bo,
              float* __restrict__ out)
{
    __shared__ float mneg[256];        // -1e8 * mask, [agent][k]
    __shared__ f16   ot[64 * 136];     // O tile f16, pitch 136 (A-frag source for out proj)

    const int tid  = threadIdx.x;
    const int lane = tid & 63;
    const int h    = __builtin_amdgcn_readfirstlane(tid >> 6);
    const int l15  = lane & 15;
    const int q    = lane >> 4;
    const long base = (long)blockIdx.x * 64;

    // stage masks (1 value/thread)
    mneg[tid] = -1e8f * (float)nmask[base * 4 + tid];
    __syncthreads();

    // per-lane bias values (col = h*32 + ct*16 + l15)
    const float bav[2] = { ba[h * 32 + l15], ba[h * 32 + 16 + l15] };
    const float bnv[2] = { bn[h * 32 + l15], bn[h * 32 + 16 + l15] };
    const float bhv[2] = { bh[h * 32 + l15], bh[h * 32 + 16 + l15] };
    const float bov    = bo[h * 16 + l15];

    const f16* wsn = ws + 8192;
    const f16* wsh = ws + 16384;
    const f16* wso = ws + 24576;

    // persistent B-fragments for the k-loop (wave h: cols 32h + 16ct + l15)
    f16x8 wn[2][2], wh[2][2];
    #pragma unroll
    for (int ct = 0; ct < 2; ++ct)
        #pragma unroll
        for (int ks = 0; ks < 2; ++ks) {
            int n = h * 32 + ct * 16 + l15;
            wn[ct][ks] = *(const f16x8*)(wsn + n * 64 + ks * 32 + q * 8);
            wh[ct][ks] = *(const f16x8*)(wsh + n * 64 + ks * 32 + q * 8);
        }

    // ---- phase A: P_a = relu(agent @ Wa + ba), kept in C-layout registers ----
    f32x4 pa[4][2];
    {
        f16x8 wa[2][2];
        #pragma unroll
        for (int ct = 0; ct < 2; ++ct)
            #pragma unroll
            for (int ks = 0; ks < 2; ++ks)
                wa[ct][ks] = *(const f16x8*)(ws + (h * 32 + ct * 16 + l15) * 64 + ks * 32 + q * 8);
        #pragma unroll
        for (int rt = 0; rt < 4; ++rt) {
            f32x4 c0 = {0.f, 0.f, 0.f, 0.f}, c1 = {0.f, 0.f, 0.f, 0.f};
            const float* ap = agent + (base + rt * 16 + l15) * 64 + q * 8;  // k = q*8 + j
            f16x8 a0 = ld_cvt8(ap);        // k in [q*8,   q*8+8)
            f16x8 a1 = ld_cvt8(ap + 32);   // k in [32+q*8, 32+q*8+8)
            c0 = MFMA(a0, wa[0][0], c0); c0 = MFMA(a1, wa[0][1], c0);
            c1 = MFMA(a0, wa[1][0], c1); c1 = MFMA(a1, wa[1][1], c1);
            #pragma unroll
            for (int r = 0; r < 4; ++r) {
                c0[r] = fmaxf(c0[r] + bav[0], 0.f);
                c1[r] = fmaxf(c1[r] + bav[1], 0.f);
            }
            pa[rt][0] = c0; pa[rt][1] = c1;
        }
    }

    // ---- fused k-loop: P_n logits + online softmax accum of P_h ----
    f32x4 oacc[4][2] = {};
    f32x4 lsum[4] = {};
    #pragma unroll
    for (int k = 0; k < 4; ++k) {
        #pragma unroll
        for (int rt = 0; rt < 4; ++rt) {
            const float* nb = neighbor + ((base + rt * 16 + l15) * 4 + k) * 64 + q * 8;
            f16x8 a0 = ld_cvt8(nb);
            f16x8 a1 = ld_cvt8(nb + 32);
            f32x4 n0 = {0.f,0.f,0.f,0.f}, n1 = {0.f,0.f,0.f,0.f};
            f32x4 h0 = {0.f,0.f,0.f,0.f}, h1 = {0.f,0.f,0.f,0.f};
            n0 = MFMA(a0, wn[0][0], n0); n0 = MFMA(a1, wn[0][1], n0);
            n1 = MFMA(a0, wn[1][0], n1); n1 = MFMA(a1, wn[1][1], n1);
            h0 = MFMA(a0, wh[0][0], h0); h0 = MFMA(a1, wh[0][1], h0);
            h1 = MFMA(a0, wh[1][0], h1); h1 = MFMA(a1, wh[1][1], h1);
            #pragma unroll
            for (int r = 0; r < 4; ++r) {
                n0[r] = fmaxf(n0[r] + bnv[0], 0.f);
                n1[r] = fmaxf(n1[r] + bnv[1], 0.f);
                h0[r] = fmaxf(h0[r] + bhv[0], 0.f);
                h1[r] = fmaxf(h1[r] + bhv[1], 0.f);
            }
            #pragma unroll
            for (int r = 0; r < 4; ++r) {
                // partial dot over this lane's col; reduce over 16 cols x 2 ct
                float tp = pa[rt][0][r] * n0[r] + pa[rt][1][r] * n1[r];
                float logit = rowsum16(tp);                 // replicated in 16 lanes
                float s = logit + mneg[(rt * 16 + q * 4 + r) * 4 + k];
                float e = __expf(s);                        // masked -> exp(-1e8) = 0
                lsum[rt][r] += e;
                float ep = (s > -1e7f) ? e : 0.f;           // (1-mask) factor
                oacc[rt][0][r] += ep * h0[r];
                oacc[rt][1][r] += ep * h1[r];
            }
        }
    }

    // ---- layout transform: oacc (C-layout) -> ot (row-major f16) ----
    #pragma unroll
    for (int rt = 0; rt < 4; ++rt)
        #pragma unroll
        for (int r = 0; r < 4; ++r) {
            float inv = 0.25f / (lsum[rt][r] + 1e-30f);     // fold mean/4 + softmax denom
            int row = rt * 16 + q * 4 + r;
            ot[row * 136 + h * 32 + l15]      = (f16)(oacc[rt][0][r] * inv);
            ot[row * 136 + h * 32 + 16 + l15] = (f16)(oacc[rt][1][r] * inv);
        }
    __syncthreads();

    // ---- out proj: Y = relu(O @ Wo + bo); wave h -> cols [16h, 16h+16) ----
    f16x8 wof[4];
    #pragma unroll
    for (int ks = 0; ks < 4; ++ks)
        wof[ks] = *(const f16x8*)(wso + (h * 16 + l15) * 128 + ks * 32 + q * 8);
    #pragma unroll
    for (int rt = 0; rt < 4; ++rt) {
        f32x4 y = {0.f, 0.f, 0.f, 0.f};
        #pragma unroll
        for (int ks = 0; ks < 4; ++ks) {
            f16x8 of = *(const f16x8*)(ot + (rt * 16 + l15) * 136 + ks * 32 + q * 8);
            y = MFMA(of, wof[ks], y);
        }
        #pragma unroll
        for (int r = 0; r < 4; ++r)
            out[(base + rt * 16 + q * 4 + r) * 64 + h * 16 + l15] = fmaxf(y[r] + bov, 0.f);
    }
}

extern "C" void kernel_launch(void* const* d_in, const int* in_sizes, int n_in,
                              void* d_out, int out_size, void* d_ws, size_t ws_size,
                              hipStream_t stream) {
    const float* agent    = (const float*)d_in[0];
    const float* neighbor = (const float*)d_in[1];
    const int*   nmask    = (const int*)d_in[2];
    const float* Wa = (const float*)d_in[3];
    const float* ba = (const float*)d_in[4];
    const float* Wn = (const float*)d_in[5];
    const float* bn = (const float*)d_in[6];
    const float* Wh = (const float*)d_in[7];
    const float* bh = (const float*)d_in[8];
    const float* Wo = (const float*)d_in[9];
    const float* bo = (const float*)d_in[10];
    float* out = (float*)d_out;
    f16* ws = (f16*)d_ws;

    prep_w<<<128, 256, 0, stream>>>(Wa, Wn, Wh, Wo, ws);

    const int n = in_sizes[0] / 64;       // 200000
    const int blocks = n / 64;            // 3125
    gat_mfma<<<blocks, 256, 0, stream>>>(agent, neighbor, nmask, ws,
                                         ba, bn, bh, bo, out);
}